// Round 8
// baseline (206.025 us; speedup 1.0000x reference)
//
#include <hip/hip_runtime.h>
#include <hip/hip_bf16.h>

// Problem dims (fixed by reference): E=8, D=2048, B=4096, 3 layers.
#define MDIM 4096
#define NDIM 2048
#define KDIM 2048
#define KTILES 32          // K / 64
#define PER_LAYER 4194304  // 2048*2048

typedef __attribute__((ext_vector_type(8))) short bf16x8;   // 8 bf16 (4 VGPRs)
typedef __attribute__((ext_vector_type(4))) float f32x4;    // MFMA accumulator

__device__ __forceinline__ unsigned short f2bf(float f) {
    unsigned u = __builtin_bit_cast(unsigned, f);
    u += 0x7FFFu + ((u >> 16) & 1u);        // round-to-nearest-even
    return (unsigned short)(u >> 16);
}

// ---------------------------------------------------------------------------
// Kernel 1: blend layer-0 experts + convert x to bf16 (W1/W2 blend is fused
// into the GEMM kernels). Reads 134MB W0 + 32MB x -> ~29us HBM-bound.
// ---------------------------------------------------------------------------
__global__ __launch_bounds__(256) void blend0_kernel(
    const float* __restrict__ W, const float* __restrict__ cb,
    const float* __restrict__ x,
    unsigned short* __restrict__ wb, unsigned short* __restrict__ xb)
{
    float c[8];
#pragma unroll
    for (int e = 0; e < 8; ++e) c[e] = cb[e];
    const unsigned wtotal4 = PER_LAYER >> 2;        // 1,048,576 float4 units
    const unsigned xtotal4 = 2097152u;              // 8M / 4
    const unsigned total = wtotal4 + xtotal4;
    unsigned stride = gridDim.x * blockDim.x;
    for (unsigned i = blockIdx.x * blockDim.x + threadIdx.x; i < total; i += stride) {
        if (i < wtotal4) {
            unsigned off = i << 2;
            const float* base = W + off;
            float4 s = make_float4(0.f, 0.f, 0.f, 0.f);
#pragma unroll
            for (int e = 0; e < 8; ++e) {
                float4 v = *(const float4*)(base + (size_t)e * PER_LAYER);
                s.x += c[e] * v.x; s.y += c[e] * v.y;
                s.z += c[e] * v.z; s.w += c[e] * v.w;
            }
            ushort4 o;
            o.x = f2bf(s.x); o.y = f2bf(s.y); o.z = f2bf(s.z); o.w = f2bf(s.w);
            *(ushort4*)(wb + off) = o;
        } else {
            unsigned j = (i - wtotal4) << 2;
            float4 v = *(const float4*)(x + j);
            ushort4 o;
            o.x = f2bf(v.x); o.y = f2bf(v.y); o.z = f2bf(v.z); o.w = f2bf(v.w);
            *(ushort4*)(xb + j) = o;
        }
    }
}

// ---------------------------------------------------------------------------
// Kernel 2: 128x128 bf16 GEMM, 2-buf LDS (64KB -> 2 blocks/CU), 256 threads
// = 4 waves (2x2), wave tile 64x64; 1 barrier + VMC(0) per K-tile; fused
// next-layer blend spread over iters t=0,4,..,28.
//   C[M,N] = A[M,K] * Bw[N,K]^T + bias, optional ELU;  wbNext = sum_e c_e W_e.
// grid = 32x16 = 512 blocks = 2 resident blocks per CU -> cross-block overlap
// fills barrier/vmcnt drains (m103/m114 mechanism).
// Staging: 8x 4KB gload_lds per K-tile; prologue fills both bufs; iter t>=1
// stages t+1 into buf (t+1)&1 (readers of that buf finished before the
// end-of-(t-1) barrier -> WAR safe). VMC(0)+BARR publishes tile t+1.
// ---------------------------------------------------------------------------
#define BARR() do { asm volatile("" ::: "memory"); __builtin_amdgcn_s_barrier(); asm volatile("" ::: "memory"); } while (0)
#define SP(N) __builtin_amdgcn_s_setprio(N)
#define VMC_IMPL(N) asm volatile("s_waitcnt vmcnt(" #N ")" ::: "memory")
#define VMC(N) VMC_IMPL(N)

template<int ACT, typename OutT, int BLEND>
__global__ __launch_bounds__(256, 2) void gemm_fused(
    const unsigned short* __restrict__ A,   // M x K bf16 bits
    const unsigned short* __restrict__ Bw,  // N x K bf16 bits
    const float* __restrict__ bias,         // N
    OutT* __restrict__ C,                   // M x N
    const float* __restrict__ Wnext,        // 8 x 2048 x 2048 f32 (or null)
    const float* __restrict__ cb,           // (8,) blend coeffs (or null)
    unsigned short* __restrict__ wbNext)    // 2048 x 2048 bf16 out (or null)
{
    __shared__ __align__(16) unsigned short lds[32768];   // 64 KB
    char* ldsc = (char*)lds;

    const int tid = threadIdx.x;
    const int wid = tid >> 6;
    const int lane = tid & 63;
    const int wr = wid >> 1;      // 0..1 (M)
    const int wc = wid & 1;       // 0..1 (N)

    // blend coeffs: load + fence BEFORE any counted vmem ops.
    float cw[8];
    if (BLEND) {
#pragma unroll
        for (int e = 0; e < 8; ++e) cw[e] = cb[e];
        VMC(0);
    }

    // bijective XCD-chunked swizzle: chunk k = blockIdx&7 gets an 8Mx8N
    // tile rectangle -> per-XCD working set A 4MB + B 4MB.
    const int k8 = blockIdx.x & 7;
    const int j = blockIdx.x >> 3;                 // 0..63
    const size_t blockM = (size_t)((k8 & 3) * 8 + (j >> 3)) * 128;
    const size_t blockN = (size_t)((k8 >> 2) * 8 + (j & 7)) * 128;

    // ds_read addressing: swizzled 16B slot within a 128B row.
    const int sw = (lane & 7) << 4;          // (row&7)<<4; row&7 == lane&7
    const int ck = (lane >> 4) << 4;         // k-slot byte base
    const int rAb = wr * 64 + (lane & 15);   // + m*16
    const int rBb = wc * 64 + (lane & 15);   // + n*16

    // staging: per 4KB call, thread t -> row 32s+(t>>3), slot (t&7)^(row&7).
    const int srow = tid >> 3;                       // 0..31
    const int scol = ((tid & 7) ^ (srow & 7)) << 3;  // element offset
    const unsigned short* aStage = A + (blockM + srow) * KDIM + scol;
    const unsigned short* bStage = Bw + (blockN + srow) * KDIM + scol;

#define STAGE_TILE(BUF, KT) do { \
    _Pragma("unroll") for (int s_ = 0; s_ < 4; ++s_) { \
        const unsigned short* ga_ = aStage + (size_t)s_ * 32 * KDIM + (size_t)(KT) * 64; \
        __builtin_amdgcn_global_load_lds((const __attribute__((address_space(1))) void*)ga_, \
            (__attribute__((address_space(3))) void*)(ldsc + (BUF) * 32768 + s_ * 4096 + tid * 16), \
            16, 0, 0); \
    } \
    _Pragma("unroll") for (int s_ = 0; s_ < 4; ++s_) { \
        const unsigned short* gb_ = bStage + (size_t)s_ * 32 * KDIM + (size_t)(KT) * 64; \
        __builtin_amdgcn_global_load_lds((const __attribute__((address_space(1))) void*)gb_, \
            (__attribute__((address_space(3))) void*)(ldsc + (BUF) * 32768 + 16384 + s_ * 4096 + tid * 16), \
            16, 0, 0); \
    } \
} while (0)

#define RD_A(BUF, M, KK) \
    (*(const bf16x8*)(ldsc + (BUF) * 32768 + (rAb + (M) * 16) * 128 + (((KK) * 64 + ck) ^ sw)))
#define RD_B(BUF, N, KK) \
    (*(const bf16x8*)(ldsc + (BUF) * 32768 + 16384 + (rBb + (N) * 16) * 128 + (((KK) * 64 + ck) ^ sw)))

    f32x4 acc[4][4];
#pragma unroll
    for (int m = 0; m < 4; ++m)
#pragma unroll
        for (int n = 0; n < 4; ++n) acc[m][n] = (f32x4){0.f, 0.f, 0.f, 0.f};

    // one blend chunk: thread blends float4 #(G*131072 + bid*256 + tid)
#define BLEND_STEP(G) do { \
    const unsigned idx_ = (unsigned)(G) * 131072u + (unsigned)blockIdx.x * 256u + (unsigned)tid; \
    const unsigned off_ = idx_ << 2; \
    const float* bs_ = Wnext + off_; \
    float4 s_ = make_float4(0.f, 0.f, 0.f, 0.f); \
    _Pragma("unroll") for (int e_ = 0; e_ < 8; ++e_) { \
        float4 v_ = *(const float4*)(bs_ + (size_t)e_ * PER_LAYER); \
        s_.x += cw[e_] * v_.x; s_.y += cw[e_] * v_.y; \
        s_.z += cw[e_] * v_.z; s_.w += cw[e_] * v_.w; } \
    ushort4 o_; \
    o_.x = f2bf(s_.x); o_.y = f2bf(s_.y); o_.z = f2bf(s_.z); o_.w = f2bf(s_.w); \
    *(ushort4*)(wbNext + off_) = o_; \
} while (0)

    // ---- prologue: tile0 -> buf0, tile1 -> buf1 ----
    STAGE_TILE(0, 0);
    STAGE_TILE(1, 1);
    VMC(8);                       // tile0 landed; tile1's 8 calls in flight
    BARR();

#pragma unroll 1
    for (int t = 0; t < KTILES; ++t) {
        const int cur = t & 1;
        bf16x8 af[4][2], bfr[4][2];
#pragma unroll
        for (int m = 0; m < 4; ++m) { af[m][0] = RD_A(cur, m, 0); af[m][1] = RD_A(cur, m, 1); }
#pragma unroll
        for (int n = 0; n < 4; ++n) { bfr[n][0] = RD_B(cur, n, 0); bfr[n][1] = RD_B(cur, n, 1); }
        if (t >= 1 && t + 1 < KTILES) STAGE_TILE(cur ^ 1, t + 1);
        if (BLEND && (t & 3) == 0) BLEND_STEP(t >> 2);
        SP(1);
#pragma unroll
        for (int kk = 0; kk < 2; ++kk)
#pragma unroll
            for (int m = 0; m < 4; ++m)
#pragma unroll
                for (int n = 0; n < 4; ++n)
                    acc[m][n] = __builtin_amdgcn_mfma_f32_16x16x32_bf16(
                        af[m][kk], bfr[n][kk], acc[m][n], 0, 0, 0);
        SP(0);
        VMC(0);                   // tile t+1 (and blend ops) drained
        BARR();
    }

    // ---- epilogue: C/D layout col=lane&15 (N), row=(lane>>4)*4+reg (M) ----
    const int crow = (lane >> 4) * 4;
    const int ccol = lane & 15;
#pragma unroll
    for (int m = 0; m < 4; ++m)
#pragma unroll
        for (int n = 0; n < 4; ++n) {
            const size_t col = blockN + wc * 64 + n * 16 + ccol;
            const float bv = bias[col];
#pragma unroll
            for (int r = 0; r < 4; ++r) {
                const size_t row = blockM + wr * 64 + m * 16 + crow + r;
                float v = acc[m][n][r] + bv;
                if (ACT) v = v > 0.f ? v : expm1f(v);
                if constexpr (sizeof(OutT) == 2) {
                    C[row * NDIM + col] = (OutT)f2bf(v);
                } else {
                    C[row * NDIM + col] = (OutT)v;
                }
            }
        }
#undef STAGE_TILE
#undef RD_A
#undef RD_B
#undef BLEND_STEP
}

// ---------------------------------------------------------------------------
// Launch: blend0+convert, then 3 chained GEMMs; GEMM0 blends W1, GEMM1
// blends W2 (overlapped with compute), GEMM2 plain.
// Workspace (ushort units): wb[3*PER_LAYER] weights, xb[8388608], y0[8388608].
// ---------------------------------------------------------------------------
extern "C" void kernel_launch(void* const* d_in, const int* in_sizes, int n_in,
                              void* d_out, int out_size, void* d_ws, size_t ws_size,
                              hipStream_t stream) {
    const float* blendw = (const float*)d_in[0];   // (8,)
    const float* x      = (const float*)d_in[1];   // (4096, 2048)
    const float* W      = (const float*)d_in[2];   // (3, 8, 2048, 2048)
    const float* Bb     = (const float*)d_in[3];   // (3, 2048)
    float* out = (float*)d_out;                    // (4096, 2048) f32

    unsigned short* wb0 = (unsigned short*)d_ws;
    unsigned short* wb1 = wb0 + PER_LAYER;
    unsigned short* wb2 = wb1 + PER_LAYER;
    unsigned short* xb  = wb2 + PER_LAYER;
    unsigned short* y0  = xb + 8388608;
    unsigned short* y1  = xb;   // reuse: xb dead after GEMM0

    blend0_kernel<<<2048, 256, 0, stream>>>(W, blendw, x, wb0, xb);

    const int grid = (MDIM / 128) * (NDIM / 128);    // 512 blocks = 2/CU
    gemm_fused<1, unsigned short, 1><<<grid, 256, 0, stream>>>(
        xb, wb0, Bb,        y0,  W + (size_t)8 * PER_LAYER,  blendw, wb1);
    gemm_fused<1, unsigned short, 1><<<grid, 256, 0, stream>>>(
        y0, wb1, Bb + 2048, y1,  W + (size_t)16 * PER_LAYER, blendw, wb2);
    gemm_fused<0, float, 0><<<grid, 256, 0, stream>>>(
        y1, wb2, Bb + 4096, out, nullptr, nullptr, nullptr);
}